// Round 1
// 1823.733 us; speedup vs baseline: 1.4036x; 1.4036x over previous
//
#include <hip/hip_runtime.h>

// SCLSTM on MI355X — R5: same-XCD L2 fast path + barrier-window pre-staging +
// fused reduce/cell phase.
//
// Dead code (verified R1-R3): s==0 forever => st==0, slot_info==tanh(sb[l]).
// Remaining: 2-layer LSTM B=64,T=512,H=512; layers pipelined on disjoint sets.
//
// R4 post-mortem: sync-latency-bound (MfmaUtil 4.4, VALU 8.4, HBM 1.3%);
// per-step 4.9us vs ~1.5us visible work. Every barrier hop = agent scope = MALL RT.
// R5: (1) a sync group (32 blocks, same blk%8) sits on ONE XCD (runtime-verified
// via HW_REG_XCC_ID, agent-scope fallback): group flags + private recurrence ring
// use plain stores + sc0 loads (L2 = intra-XCD coherence point). ring0 (A->B)
// stays agent. (2) non-recurrent K-half (x(t+1)/h0(t+1)) staged inside the
// barrier window -> off critical path. (3) reduce fused into cell update
// (part_lds stride 17, per-thread bias regs): one fewer LDS pass + barrier.

typedef unsigned short ushort;
typedef unsigned long long u64;
using bfrag = __attribute__((ext_vector_type(8))) short;
using cfrag = __attribute__((ext_vector_type(4))) float;
using i4    = __attribute__((ext_vector_type(4))) int;

constexpr int NBLK = 256, NTHR = 512;
constexpr int Bsz = 64, Tt = 512, Hsz = 512;
constexpr int D0 = 8;                     // ring0 (A->B) depth
constexpr int DP = 2;                     // private recurrence ring depth

constexpr long long OUT_HT = (long long)Bsz * Tt * Hsz;
constexpr long long OUT_CT = OUT_HT + (long long)Bsz * 2 * Hsz;
constexpr long long OUT_ST = OUT_CT + (long long)Bsz * 2 * Hsz;

// ws layout (bytes)
constexpr int WS_SLOTS_A = 0;                                 // 4 grp x 32 x 16 ints
constexpr int WS_SLOTS_B = 8 * 1024;
constexpr int WS_PROG_A  = 16 * 1024;
constexpr int WS_PROG_B  = 17 * 1024;
constexpr int WS_XCC     = 18 * 1024;                         // 2 x 4 x 32 x 16 ints
constexpr int WS_RING0   = 64 * 1024;                         // D0 x 64 x 512 ushort
constexpr int WS_RING1   = WS_RING0 + D0 * Bsz * Hsz * 2;     // DP x ... (B private)
constexpr int WS_RINGA   = WS_RING1 + DP * Bsz * Hsz * 2;     // DP x ... (A private)
constexpr int WS_TOTAL   = WS_RINGA + DP * Bsz * Hsz * 2;     // ~832KB

__global__ __launch_bounds__(256) void sclstm_init(float* __restrict__ ws,
                                                   float* __restrict__ out) {
    int i = blockIdx.x * blockDim.x + threadIdx.x, st = gridDim.x * blockDim.x;
    for (int k = i; k < WS_TOTAL / 4; k += st) ws[k] = 0.f;
    for (int k = i; k < Bsz * 128; k += st) out[OUT_ST + k] = 0.f;  // st == 0 always
}

__device__ __forceinline__ float sigm(float x) { return 1.f / (1.f + __expf(-x)); }
__device__ __forceinline__ float ftanh(float x) {
    float e = __expf(2.f * x);
    return 1.f - 2.f / (e + 1.f);
}
__device__ __forceinline__ ushort f2bf(float f) {
    unsigned u = __builtin_bit_cast(unsigned, f);
    u += 0x7FFFu + ((u >> 16) & 1u);
    return (ushort)(u >> 16);
}
__device__ __forceinline__ int aload(const int* p) {
    return __hip_atomic_load(p, __ATOMIC_RELAXED, __HIP_MEMORY_SCOPE_AGENT);
}
__device__ __forceinline__ int load_sc0(const int* p) {   // bypass L1, read own-XCD L2
    int v;
    asm volatile("global_load_dword %0, %1, off sc0\n\ts_waitcnt vmcnt(0)"
                 : "=v"(v) : "v"(p) : "memory");
    return v;
}
__device__ __forceinline__ void spin_agent(const int* p, int v) {
    int it = 0;
    while (aload(p) < v) {
        __builtin_amdgcn_s_sleep(1);
        if (((++it) & 1023) == 0)
            __builtin_amdgcn_fence(__ATOMIC_ACQUIRE, "agent");  // safety net only
    }
}
__device__ __forceinline__ void spin_f(const int* p, int v, int fast) {
    if (fast) {
        int it = 0;
        while (load_sc0(p) < v) {
            __builtin_amdgcn_s_sleep(1);
            if (((++it) & 63) == 0)
                __builtin_amdgcn_fence(__ATOMIC_ACQUIRE, "agent");  // safety net only
        }
    } else {
        spin_agent(p, v);
    }
}
__device__ __forceinline__ void st_flag(int* p, int v, int fast) {
    if (fast) __hip_atomic_store(p, v, __ATOMIC_RELAXED, __HIP_MEMORY_SCOPE_WORKGROUP);
    else      __hip_atomic_store(p, v, __ATOMIC_RELAXED, __HIP_MEMORY_SCOPE_AGENT);
}
__device__ __forceinline__ void st_h(ushort* p, ushort v, int fast) {
    if (fast) __hip_atomic_store(p, v, __ATOMIC_RELAXED, __HIP_MEMORY_SCOPE_WORKGROUP);
    else      __hip_atomic_store(p, v, __ATOMIC_RELAXED, __HIP_MEMORY_SCOPE_AGENT);
}
__device__ __forceinline__ bfrag pack2(u64 q0, u64 q1) {
    bfrag v;
    v[0]=(short)(ushort)(q0); v[1]=(short)(ushort)(q0 >> 16);
    v[2]=(short)(ushort)(q0 >> 32); v[3]=(short)(ushort)(q0 >> 48);
    v[4]=(short)(ushort)(q1); v[5]=(short)(ushort)(q1 >> 16);
    v[6]=(short)(ushort)(q1 >> 32); v[7]=(short)(ushort)(q1 >> 48);
    return v;
}

__global__ __launch_bounds__(NTHR, 2) void sclstm_main(
    const float* __restrict__ inputs,   // (B,T,512) fp32
    const float* __restrict__ gW,       // (2, 2048, 1024) fp32
    const float* __restrict__ gb,       // (2, 2048)
    const float* __restrict__ sbias,    // (2, 512)
    float* __restrict__ out,
    float* __restrict__ ws)
{
    __shared__ __attribute__((aligned(16))) ushort frag_lds[32 * 512]; // 32 ks x 1KB
    __shared__ float part_lds[64 * 17 * 2];   // [(lrow*17+col)*2 + g], stride-17 pad
    __shared__ int fast_sh;

    char* wsb = (char*)ws;
    const int tid = threadIdx.x, blk = blockIdx.x;
    const int setB = blk & 1;                  // 0: layer0 (producer), 1: layer1
    const int grp = (blk >> 1) & 3;            // batch tile
    const int myidx = blk >> 3;                // 0..31 feature tile within group
    const int L = setB;
    const int b0 = grp * 16, m0 = myidx * 16;

    int* slots     = (int*)(wsb + (setB ? WS_SLOTS_B : WS_SLOTS_A)) + grp * 32 * 16;
    int* prog_self = (int*)(wsb + (setB ? WS_PROG_B : WS_PROG_A)) + grp * 16;
    int* prog_up   = (int*)(wsb + WS_PROG_A) + grp * 16;   // B waits: h0(t) ready
    int* prog_down = (int*)(wsb + WS_PROG_B) + grp * 16;   // A ring0 backpressure
    ushort* ring0 = (ushort*)(wsb + WS_RING0);
    ushort* ring1 = (ushort*)(wsb + WS_RING1);
    ushort* ringA = (ushort*)(wsb + WS_RINGA);
    ushort* ring_own = setB ? ring1 : ringA;   // private recurrence ring (L2-local)

    const int lane = tid & 63, wave = tid >> 6;
    const int tau = wave & 3, g = wave >> 2;   // gate tile, K-half (512 each)
    const int q = lane >> 4, lm = lane & 15;

    // ---- one-time: weights -> A-fragments (16 ksteps) = 64 VGPRs ----
    bfrag wv[16];
    {
        const int grow = tau * 512 + m0 + lm;
        const float* wrow = gW + ((size_t)L * 2048 + grow) * 1024 + g * 512 + q * 8;
        #pragma unroll
        for (int j = 0; j < 16; ++j) {
            const float* src = wrow + j * 32;
            float4 a = *(const float4*)src, b = *(const float4*)(src + 4);
            bfrag v;
            v[0]=(short)f2bf(a.x); v[1]=(short)f2bf(a.y); v[2]=(short)f2bf(a.z); v[3]=(short)f2bf(a.w);
            v[4]=(short)f2bf(b.x); v[5]=(short)f2bf(b.y); v[6]=(short)f2bf(b.z); v[7]=(short)f2bf(b.w);
            wv[j] = v;
        }
    }
    // ---- per-cell constants: 4 gate biases in regs, slot const, cell state ----
    float bias4[4] = {0.f, 0.f, 0.f, 0.f};
    float slotc = 0.f, c = 0.f;                // tid<256 = (mi=tid&15, b3=tid>>4)
    if (tid < 256) {
        const int mi = tid & 15;
        #pragma unroll
        for (int tg = 0; tg < 4; ++tg) bias4[tg] = gb[L * 2048 + tg * 512 + m0 + mi];
        slotc = ftanh(sbias[L * 512 + m0 + mi]);
    }

    // ---- runtime check: is this sync group on one XCD? (agent fallback if not) ----
    int fast;
    {
        unsigned xcc = (unsigned)__builtin_amdgcn_s_getreg((31 << 11) | 20) & 0xFu; // HW_REG_XCC_ID
        int* xarr = (int*)(wsb + WS_XCC) + (setB * 4 + grp) * 32 * 16;
        if (tid == 0) {
            __hip_atomic_store(xarr + myidx * 16, (int)xcc + 1,
                               __ATOMIC_RELAXED, __HIP_MEMORY_SCOPE_AGENT);
            int ok = 1, ref = 0;
            for (int i = 0; i < 32; ++i) {
                int v;
                while ((v = aload(xarr + i * 16)) == 0) __builtin_amdgcn_s_sleep(2);
                if (i == 0) ref = v; else ok &= (v == ref);
            }
            fast_sh = ok;
        }
        __syncthreads();
        fast = fast_sh;
    }

    // stage the non-recurrent K-half (rows 0..15): A: x(tt); B: h0(tt) from ring0
    auto stage_nonrec = [&](int tt) {
        #pragma unroll
        for (int it = 0; it < 2; ++it) {
            const int ks = it * 8 + wave;      // 0..15
            bfrag v;
            if (!setB) {
                const float* xs = inputs + ((size_t)(b0 + lm) * Tt + tt) * 512 + ks * 32 + q * 8;
                float4 a = *(const float4*)xs, b = *(const float4*)(xs + 4);
                v[0]=(short)f2bf(a.x); v[1]=(short)f2bf(a.y); v[2]=(short)f2bf(a.z); v[3]=(short)f2bf(a.w);
                v[4]=(short)f2bf(b.x); v[5]=(short)f2bf(b.y); v[6]=(short)f2bf(b.z); v[7]=(short)f2bf(b.w);
            } else {
                const ushort* hs = ring0 + (size_t)(tt & (D0 - 1)) * (Bsz * Hsz)
                                 + (b0 + lm) * 512 + ks * 32 + q * 8;
                u64 q0 = __hip_atomic_load((const u64*)hs, __ATOMIC_RELAXED, __HIP_MEMORY_SCOPE_AGENT);
                u64 q1 = __hip_atomic_load((const u64*)(hs + 4), __ATOMIC_RELAXED, __HIP_MEMORY_SCOPE_AGENT);
                v = pack2(q0, q1);
            }
            *(bfrag*)&frag_lds[ks * 512 + lane * 8] = v;
        }
    };

    // ---- prologue: pre-stage non-recurrent half for t=0 ----
    if (setB) {
        if (tid == 0) spin_agent(prog_up, 1);
        __syncthreads();
    }
    stage_nonrec(0);

    for (int t = 0; t < Tt; ++t) {
        const int rsp = (t - 1) & (DP - 1), rsc = t & (DP - 1);

        // ---- recurrent staging (rows 16..31) from own ring, guarded by group barrier ----
        {
            const ushort* hb_ = ring_own + (size_t)rsp * (Bsz * Hsz) + (b0 + lm) * 512 + q * 8;
            const ushort* p0 = hb_ + wave * 32;          // kk = wave
            const ushort* p1 = hb_ + (wave + 8) * 32;    // kk = wave+8
            bfrag v0, v1;
            if (fast) {
                i4 w0, w1;
                asm volatile(
                    "global_load_dwordx4 %0, %2, off sc0\n\t"
                    "global_load_dwordx4 %1, %3, off sc0\n\t"
                    "s_waitcnt vmcnt(0)"
                    : "=&v"(w0), "=&v"(w1) : "v"(p0), "v"(p1) : "memory");
                v0 = __builtin_bit_cast(bfrag, w0);
                v1 = __builtin_bit_cast(bfrag, w1);
            } else {
                u64 a0 = __hip_atomic_load((const u64*)p0, __ATOMIC_RELAXED, __HIP_MEMORY_SCOPE_AGENT);
                u64 a1 = __hip_atomic_load((const u64*)(p0 + 4), __ATOMIC_RELAXED, __HIP_MEMORY_SCOPE_AGENT);
                u64 c0 = __hip_atomic_load((const u64*)p1, __ATOMIC_RELAXED, __HIP_MEMORY_SCOPE_AGENT);
                u64 c1 = __hip_atomic_load((const u64*)(p1 + 4), __ATOMIC_RELAXED, __HIP_MEMORY_SCOPE_AGENT);
                v0 = pack2(a0, a1); v1 = pack2(c0, c1);
            }
            *(bfrag*)&frag_lds[(16 + wave) * 512 + lane * 8] = v0;
            *(bfrag*)&frag_lds[(24 + wave) * 512 + lane * 8] = v1;
        }
        __syncthreads();                                  // S1: frag ready

        // ---- MFMA: 16 ksteps over this wave's K-half, 2 chains ----
        cfrag C0 = {0.f, 0.f, 0.f, 0.f}, C1 = {0.f, 0.f, 0.f, 0.f};
        #pragma unroll
        for (int j = 0; j < 16; j += 2) {
            bfrag Bf0 = *(const bfrag*)&frag_lds[(g * 16 + j) * 512 + lane * 8];
            C0 = __builtin_amdgcn_mfma_f32_16x16x32_bf16(wv[j], Bf0, C0, 0, 0, 0);
            bfrag Bf1 = *(const bfrag*)&frag_lds[(g * 16 + j + 1) * 512 + lane * 8];
            C1 = __builtin_amdgcn_mfma_f32_16x16x32_bf16(wv[j + 1], Bf1, C1, 0, 0, 0);
        }
        #pragma unroll
        for (int reg = 0; reg < 4; ++reg) {
            const int lrow = tau * 16 + q * 4 + reg;      // C row (m89 layout)
            part_lds[(lrow * 17 + lm) * 2 + g] = C0[reg] + C1[reg];
        }
        __syncthreads();                                  // S2: partials ready

        // ---- fused reduce + cell update (direct part_lds reads, reg biases) ----
        float hn = 0.f, cn = 0.f;
        if (tid < 256) {
            const int mi = tid & 15, b3 = tid >> 4;
            float gs[4];
            #pragma unroll
            for (int tg = 0; tg < 4; ++tg) {
                float2 p = *(const float2*)&part_lds[((tg * 16 + mi) * 17 + b3) * 2];
                gs[tg] = p.x + p.y + bias4[tg];
            }
            cn = sigm(gs[1]) * c + sigm(gs[0]) * ftanh(gs[3]) + slotc;
            hn = sigm(gs[2]) * ftanh(cn);
            c = cn;
            const ushort hb16 = f2bf(hn);
            const size_t poff = (size_t)(b0 + b3) * 512 + m0 + mi;
            st_h(ring_own + (size_t)rsc * (Bsz * Hsz) + poff, hb16, fast);
            if (!setB)  // cross-XCD copy for layer 1 (agent scope)
                __hip_atomic_store(ring0 + (size_t)(t & (D0 - 1)) * (Bsz * Hsz) + poff,
                                   hb16, __ATOMIC_RELAXED, __HIP_MEMORY_SCOPE_AGENT);
        }
        __syncthreads();   // S4: drains vmcnt per wave -> ring stores at coherence pt
        if (tid == 0) st_flag(&slots[myidx * 16], t + 1, fast);

        // ---- barrier window: overlap with the group-barrier round trip ----
        if (t + 1 < Tt) {
            if (setB) {
                if (tid == 0) spin_agent(prog_up, t + 2);  // h0(t+1) ready?
                __syncthreads();
            } else if ((t + 1) >= D0 && tid == 0) {
                spin_agent(prog_down, t + 2 - D0);         // ring0 backpressure
            }
            stage_nonrec(t + 1);                           // rows 0..15 for next step
        }
        if (tid < 256) {                                   // deferred output stores
            const int mi = tid & 15, b3 = tid >> 4;
            if (setB)
                out[((size_t)(b0 + b3) * Tt + t) * Hsz + m0 + mi] = hn;
            if (t == Tt - 1) {
                out[OUT_HT + (size_t)(b0 + b3) * 1024 + L * 512 + m0 + mi] = hn;
                out[OUT_CT + (size_t)(b0 + b3) * 1024 + L * 512 + m0 + mi] = cn;
            }
        }
        if (tid < 32) spin_f(&slots[tid * 16], t + 1, fast);
        if (myidx == 0 && tid == 0)
            __hip_atomic_store(prog_self, t + 1, __ATOMIC_RELAXED, __HIP_MEMORY_SCOPE_AGENT);
        __syncthreads();                                   // S5: barrier confirmed
    }
}

extern "C" void kernel_launch(void* const* d_in, const int* in_sizes, int n_in,
                              void* d_out, int out_size, void* d_ws, size_t ws_size,
                              hipStream_t stream) {
    (void)in_sizes; (void)n_in; (void)out_size; (void)ws_size;
    const float* inputs = (const float*)d_in[0];
    const float* gW = (const float*)d_in[5];
    const float* gb = (const float*)d_in[6];
    const float* sbias = (const float*)d_in[8];
    float* out = (float*)d_out;
    float* ws = (float*)d_ws;

    hipLaunchKernelGGL(sclstm_init, dim3(256), dim3(256), 0, stream, ws, out);
    hipLaunchKernelGGL(sclstm_main, dim3(NBLK), dim3(NTHR), 0, stream,
                       inputs, gW, gb, sbias, out, ws);
}